// Round 1
// baseline (1722.434 us; speedup 1.0000x reference)
//
#include <hip/hip_runtime.h>
#include <hip/hip_bf16.h>

// Problem constants
#define BB 32
#define NN 1025
#define CC 512
#define HH 8
#define HD 64
#define MM (BB * NN)   // 32800
#define SCALE 0.125f

// ---------------------------------------------------------------------------
// Tiled fp32 GEMM: out = A(MxK) @ B(KxN) + bias
// MODE 0: scatter columns into q/k/v buffers (out points at q; k=q+M*512, v=...)
// MODE 1: plain row-major output
// 64x64 tile, BK=16, 256 threads, 4x4 micro-tile per thread.
// ---------------------------------------------------------------------------
template <int MODE>
__global__ __launch_bounds__(256) void gemm64_kernel(
    const float* __restrict__ A, const float* __restrict__ B,
    const float* __restrict__ bias, float* __restrict__ out,
    int M, int N, int K)
{
    __shared__ float As[16][68];  // [k][m], padded
    __shared__ float Bs[16][68];  // [k][n], padded

    const int tid = threadIdx.x;
    const int tx = tid & 15;        // output col group
    const int ty = tid >> 4;        // output row group
    const int n0 = blockIdx.x * 64;
    const int m0 = blockIdx.y * 64;

    const int ac = tid & 15;        // k-index for A load
    const int ar = tid >> 4;        // m-group for A load
    const int bc = tid & 63;        // n-index for B load
    const int br = tid >> 6;        // k-group for B load

    float acc[4][4] = {};

    for (int k0 = 0; k0 < K; k0 += 16) {
#pragma unroll
        for (int i = 0; i < 4; i++) {
            int m = ar + 16 * i;
            int gm = m0 + m;
            As[ac][m] = (gm < M) ? A[(size_t)gm * K + k0 + ac] : 0.f;
        }
#pragma unroll
        for (int i = 0; i < 4; i++) {
            int kk = br + 4 * i;
            Bs[kk][bc] = B[(size_t)(k0 + kk) * N + n0 + bc];
        }
        __syncthreads();
#pragma unroll
        for (int kk = 0; kk < 16; kk++) {
            float4 a4 = *(const float4*)&As[kk][ty * 4];
            float4 b4 = *(const float4*)&Bs[kk][tx * 4];
            float a[4] = {a4.x, a4.y, a4.z, a4.w};
            float b[4] = {b4.x, b4.y, b4.z, b4.w};
#pragma unroll
            for (int i = 0; i < 4; i++)
#pragma unroll
                for (int j = 0; j < 4; j++)
                    acc[i][j] = fmaf(a[i], b[j], acc[i][j]);
        }
        __syncthreads();
    }

#pragma unroll
    for (int i = 0; i < 4; i++) {
        int gm = m0 + ty * 4 + i;
        if (gm >= M) continue;
#pragma unroll
        for (int j = 0; j < 4; j++) {
            int gn = n0 + tx * 4 + j;
            float val = acc[i][j] + bias[gn];
            if (MODE == 0) {
                int s = gn >> 9;       // 0:q 1:k 2:v
                int c = gn & 511;
                out[((size_t)s * MM + gm) * CC + c] = val;
            } else {
                out[(size_t)gm * N + gn] = val;
            }
        }
    }
}

// ---------------------------------------------------------------------------
// Column softmax stats over N per (b, c): online max + sum(exp)
// ---------------------------------------------------------------------------
__global__ __launch_bounds__(256) void softmax_stats_kernel(
    const float* __restrict__ k, float* __restrict__ colmax, float* __restrict__ colsum)
{
    int c = blockIdx.x * 256 + threadIdx.x;  // 0..511
    int b = blockIdx.y;
    const float* kcol = k + (size_t)b * NN * CC + c;
    float m = kcol[0];
    float s = 1.f;
    for (int n = 1; n < NN; n++) {
        float val = kcol[(size_t)n * CC];
        float nm = fmaxf(m, val);
        s = s * __expf(m - nm) + __expf(val - nm);
        m = nm;
    }
    colmax[b * CC + c] = m;
    colsum[b * CC + c] = s;
}

// ---------------------------------------------------------------------------
// ksv[b,h,kk,vv] = sum_n softmax(k)[b,n,h,kk] * v[b,n,h,vv]
// One block per (b,h). 256 threads, 4x4 accum each (64x64 output).
// ---------------------------------------------------------------------------
__global__ __launch_bounds__(256) void ksv_kernel(
    const float* __restrict__ k, const float* __restrict__ v,
    const float* __restrict__ colmax, const float* __restrict__ colsum,
    float* __restrict__ ksv)
{
    int bh = blockIdx.x;
    int b = bh >> 3, h = bh & 7;
    __shared__ float ke[4][64];
    __shared__ float ve[4][64];
    __shared__ float cm[64];

    int tid = threadIdx.x;
    int tx = tid & 15, ty = tid >> 4;
    if (tid < 64) cm[tid] = colmax[b * CC + h * HD + tid];
    __syncthreads();

    float acc[4][4] = {};
    for (int n0 = 0; n0 < NN; n0 += 4) {
#pragma unroll
        for (int i = 0; i < 2; i++) {
            int idx = tid + i * 256;          // 0..511
            int r = idx >> 7;                 // row 0..3
            int half = (idx >> 6) & 1;        // 0: k, 1: v
            int cc = idx & 63;
            int n = n0 + r;
            float val = 0.f;
            if (n < NN)
                val = (half ? v : k)[((size_t)b * NN + n) * CC + h * HD + cc];
            if (half)
                ve[r][cc] = val;
            else
                ke[r][cc] = (n < NN) ? __expf(val - cm[cc]) : 0.f;
        }
        __syncthreads();
#pragma unroll
        for (int r = 0; r < 4; r++) {
            float4 a4 = *(const float4*)&ke[r][ty * 4];
            float4 b4 = *(const float4*)&ve[r][tx * 4];
            float a[4] = {a4.x, a4.y, a4.z, a4.w};
            float bv[4] = {b4.x, b4.y, b4.z, b4.w};
#pragma unroll
            for (int i = 0; i < 4; i++)
#pragma unroll
                for (int j = 0; j < 4; j++)
                    acc[i][j] = fmaf(a[i], bv[j], acc[i][j]);
        }
        __syncthreads();
    }

#pragma unroll
    for (int i = 0; i < 4; i++) {
        float inv = 1.f / colsum[b * CC + h * HD + ty * 4 + i];
#pragma unroll
        for (int j = 0; j < 4; j++)
            ksv[(size_t)bh * 4096 + (ty * 4 + i) * 64 + tx * 4 + j] = acc[i][j] * inv;
    }
}

// ---------------------------------------------------------------------------
// att[b,n,h,:] = SCALE * q[b,n,h,:] @ ksv[b,h,:,:]   (writes ALL n incl. n=0)
// Block: 64 n-rows x one (b,h). 256 threads, 4x4 each.
// ---------------------------------------------------------------------------
__global__ __launch_bounds__(256) void factor_att_kernel(
    const float* __restrict__ q, const float* __restrict__ ksv, float* __restrict__ att)
{
    int bh = blockIdx.y;
    int b = bh >> 3, h = bh & 7;
    int n0 = blockIdx.x * 64;
    __shared__ float qs[64][68];  // [kk][row]
    __shared__ float ks[64][68];  // [kk][vv]

    int tid = threadIdx.x;
    int tx = tid & 15, ty = tid >> 4;

    const float* kbase = ksv + (size_t)bh * 4096;
#pragma unroll
    for (int i = 0; i < 16; i++) {
        int idx = tid + i * 256;
        int kk = idx >> 6, vv = idx & 63;
        ks[kk][vv] = kbase[idx];
    }
#pragma unroll
    for (int i = 0; i < 16; i++) {
        int idx = tid + i * 256;
        int r = idx >> 6, cc = idx & 63;
        int n = n0 + r;
        qs[cc][r] = (n < NN) ? q[((size_t)b * NN + n) * CC + h * HD + cc] : 0.f;
    }
    __syncthreads();

    float acc[4][4] = {};
#pragma unroll 8
    for (int kk = 0; kk < 64; kk++) {
        float4 a4 = *(const float4*)&qs[kk][ty * 4];
        float4 b4 = *(const float4*)&ks[kk][tx * 4];
        float a[4] = {a4.x, a4.y, a4.z, a4.w};
        float bv[4] = {b4.x, b4.y, b4.z, b4.w};
#pragma unroll
        for (int i = 0; i < 4; i++)
#pragma unroll
            for (int j = 0; j < 4; j++)
                acc[i][j] = fmaf(a[i], bv[j], acc[i][j]);
    }

#pragma unroll
    for (int i = 0; i < 4; i++) {
        int n = n0 + ty * 4 + i;
        if (n >= NN) continue;
#pragma unroll
        for (int j = 0; j < 4; j++)
            att[((size_t)b * NN + n) * CC + h * HD + tx * 4 + j] = SCALE * acc[i][j];
    }
}

// ---------------------------------------------------------------------------
// CRPE: att[b, 1+pix, c] += q[b, 1+pix, c] * (dwconv(v_img)[pix, c] + bias[c])
// One thread per (b, pix, c). Kernel size 3/5/7 by channel range (wave-uniform).
// ---------------------------------------------------------------------------
__global__ __launch_bounds__(256) void conv_ev_kernel(
    const float* __restrict__ v, const float* __restrict__ q,
    const float* __restrict__ ck3, const float* __restrict__ cb3,
    const float* __restrict__ ck5, const float* __restrict__ cb5,
    const float* __restrict__ ck7, const float* __restrict__ cb7,
    float* __restrict__ att)
{
    int t = blockIdx.x * 256 + threadIdx.x;  // B*1024*512 total
    int c = t & 511;
    int pix = (t >> 9) & 1023;
    int b = t >> 19;
    int y = pix >> 5, x = pix & 31;

    const float* w;
    int ksz, nch;
    float sum;
    if (c < 128)      { ksz = 3; nch = 128; w = ck3 + c;         sum = cb3[c]; }
    else if (c < 320) { ksz = 5; nch = 192; w = ck5 + (c - 128); sum = cb5[c - 128]; }
    else              { ksz = 7; nch = 192; w = ck7 + (c - 320); sum = cb7[c - 320]; }
    int pad = ksz >> 1;

    for (int dy = -pad; dy <= pad; dy++) {
        int yy = y + dy;
        if (yy < 0 || yy >= 32) continue;
        for (int dx = -pad; dx <= pad; dx++) {
            int xx = x + dx;
            if (xx < 0 || xx >= 32) continue;
            size_t vi = ((size_t)b * NN + 1 + yy * 32 + xx) * CC + c;
            sum = fmaf(v[vi], w[((dy + pad) * ksz + (dx + pad)) * nch], sum);
        }
    }
    size_t oi = ((size_t)b * NN + 1 + pix) * CC + c;
    att[oi] += q[oi] * sum;
}

// ---------------------------------------------------------------------------
extern "C" void kernel_launch(void* const* d_in, const int* in_sizes, int n_in,
                              void* d_out, int out_size, void* d_ws, size_t ws_size,
                              hipStream_t stream)
{
    const float* x     = (const float*)d_in[0];
    const float* Wqkv  = (const float*)d_in[1];
    const float* bqkv  = (const float*)d_in[2];
    const float* Wproj = (const float*)d_in[3];
    const float* bproj = (const float*)d_in[4];
    const float* ck3   = (const float*)d_in[5];
    const float* cb3   = (const float*)d_in[6];
    const float* ck5   = (const float*)d_in[7];
    const float* cb5   = (const float*)d_in[8];
    const float* ck7   = (const float*)d_in[9];
    const float* cb7   = (const float*)d_in[10];
    float* out = (float*)d_out;

    // workspace layout (floats):
    float* q      = (float*)d_ws;                    // M*C
    float* kbuf   = q + (size_t)MM * CC;             // M*C
    float* v      = kbuf + (size_t)MM * CC;          // M*C
    float* colmax = v + (size_t)MM * CC;             // B*C
    float* colsum = colmax + BB * CC;                // B*C
    float* ksv    = colsum + BB * CC;                // B*H*64*64
    float* att    = kbuf;                            // reuse k buffer after ksv

    // 1) qkv = x @ Wqkv + bqkv  -> scatter to q/k/v
    {
        dim3 grid(1536 / 64, (MM + 63) / 64);
        gemm64_kernel<0><<<grid, 256, 0, stream>>>(x, Wqkv, bqkv, q, MM, 1536, 512);
    }
    // 2) softmax stats along N for k
    {
        dim3 grid(CC / 256, BB);
        softmax_stats_kernel<<<grid, 256, 0, stream>>>(kbuf, colmax, colsum);
    }
    // 3) ksv
    ksv_kernel<<<BB * HH, 256, 0, stream>>>(kbuf, v, colmax, colsum, ksv);
    // 4) att = SCALE * q @ ksv   (kbuf now dead -> att aliases it)
    {
        dim3 grid((NN + 63) / 64, BB * HH);
        factor_att_kernel<<<grid, 256, 0, stream>>>(q, ksv, att);
    }
    // 5) att += q * (dwconv(v) + cb)   for n >= 1
    conv_ev_kernel<<<(BB * 1024 * 512) / 256, 256, 0, stream>>>(
        v, q, ck3, cb3, ck5, cb5, ck7, cb7, att);
    // 6) out = att @ Wproj + bproj
    {
        dim3 grid(512 / 64, (MM + 63) / 64);
        gemm64_kernel<1><<<grid, 256, 0, stream>>>(att, Wproj, bproj, out, MM, 512, 512);
    }
}

// Round 2
// 416.010 us; speedup vs baseline: 4.1404x; 4.1404x over previous
//
#include <hip/hip_runtime.h>
#include <hip/hip_bf16.h>

#define BB 32
#define NN 1025
#define CC 512
#define HH 8
#define HD 64
#define MM (BB * NN)        // 32800
#define MP 32896            // 257 * 128 (padded M)
#define KK 512
#define SCALE 0.125f

typedef unsigned short u16;
typedef __attribute__((ext_vector_type(4))) unsigned short u16x4;
typedef __attribute__((ext_vector_type(8))) unsigned short u16x8;
typedef __attribute__((ext_vector_type(4))) float f32x4;
typedef __attribute__((ext_vector_type(8))) __bf16 bf16x8;

__device__ __forceinline__ u16 f2bf(float f) {
    unsigned u = __float_as_uint(f);
    unsigned r = (u + 0x7FFFu + ((u >> 16) & 1u)) >> 16;
    return (u16)r;
}
__device__ __forceinline__ float bf2f(u16 h) {
    return __uint_as_float((unsigned)h << 16);
}

__device__ __forceinline__ void gload16(const u16* g, u16* l) {
    __builtin_amdgcn_global_load_lds(
        (const __attribute__((address_space(1))) unsigned int*)g,
        (__attribute__((address_space(3))) unsigned int*)l, 16, 0, 0);
}

// ---------------------------------------------------------------------------
// convert x (fp32 [MM][512]) -> xbf (bf16 [MP][512]), zero pad rows
// ---------------------------------------------------------------------------
__global__ __launch_bounds__(256) void convert_x_kernel(
    const float* __restrict__ x, u16* __restrict__ xbf)
{
    size_t t = (size_t)blockIdx.x * 256 + threadIdx.x;   // one thread per 8 elems
    size_t base = t * 8;
    u16x8 o;
    if (base < (size_t)MM * CC) {
        f32x4 a = *(const f32x4*)&x[base];
        f32x4 b = *(const f32x4*)&x[base + 4];
#pragma unroll
        for (int j = 0; j < 4; j++) { o[j] = f2bf(a[j]); o[j + 4] = f2bf(b[j]); }
    } else {
#pragma unroll
        for (int j = 0; j < 8; j++) o[j] = 0;
    }
    *(u16x8*)&xbf[base] = o;
}

// ---------------------------------------------------------------------------
// transpose+convert weights: Wt[n][k] = bf16(W[k][n]);  K = 512
// ---------------------------------------------------------------------------
__global__ __launch_bounds__(256) void convert_wt_kernel(
    const float* __restrict__ W, u16* __restrict__ Wt, int N)
{
    int t = blockIdx.x * 256 + threadIdx.x;   // per 8-run along k
    int n = t >> 6;                           // K/8 = 64
    int k0 = (t & 63) * 8;
    u16x8 o;
#pragma unroll
    for (int j = 0; j < 8; j++) o[j] = f2bf(W[(size_t)(k0 + j) * N + n]);
    *(u16x8*)&Wt[(size_t)n * KK + k0] = o;
}

// ---------------------------------------------------------------------------
// bf16 MFMA GEMM: out = A[MP][512] @ Bt[N][512]^T + bias
// 128x128 tile, BK=32, 4 waves (2x2), 4x4 frags of 16x16x32, gload_lds staging
// MODE 0: scatter bf16 into q/k/v planes (outv = q plane; planes contiguous)
// MODE 1: fp32 output [MM][N], guarded
// ---------------------------------------------------------------------------
template <int MODE, int NSZ>
__global__ __launch_bounds__(256) void gemm_bf16_kernel(
    const u16* __restrict__ A, const u16* __restrict__ Bt,
    const float* __restrict__ bias, void* __restrict__ outv)
{
    __shared__ __align__(16) u16 lds[2][2][4096];   // [buf][A/B][128 rows x 32 k]

    const int t  = threadIdx.x;
    const int m0 = blockIdx.y * 128;
    const int n0 = blockIdx.x * 128;

    // staging addresses (chunk: 64 rows x 32 k = 4KB; 2 chunks per tile)
    const int srow = t >> 2;
    const int ps   = t & 3;
    const int ls   = ps ^ ((srow >> 1) & 3);        // logical k-slot (swizzle)
    const u16* gA = A  + (size_t)(m0 + srow) * KK + ls * 8;
    const u16* gB = Bt + (size_t)(n0 + srow) * KK + ls * 8;

    // fragment read addresses
    const int l  = t & 63;
    const int w  = t >> 6;
    const int wm = (w >> 1) * 64;
    const int wn = (w & 1) * 64;
    const int lr = l & 15;
    const int s  = l >> 4;
    const int ra = wm + lr;
    const int rb = wn + lr;
    const int offA = ra * 32 + (s ^ ((ra >> 1) & 3)) * 8;   // u16 elems
    const int offB = rb * 32 + (s ^ ((rb >> 1) & 3)) * 8;

    f32x4 acc[4][4] = {};

#define STAGE(buf, kk_) do {                                        \
        gload16(gA + (kk_),           &lds[buf][0][t * 8]);         \
        gload16(gA + 64 * KK + (kk_), &lds[buf][0][2048 + t * 8]);  \
        gload16(gB + (kk_),           &lds[buf][1][t * 8]);         \
        gload16(gB + 64 * KK + (kk_), &lds[buf][1][2048 + t * 8]);  \
    } while (0)

    STAGE(0, 0);
    __syncthreads();

    int cur = 0;
    for (int step = 0; step < 16; ++step) {
        if (step < 15) STAGE(cur ^ 1, (step + 1) * 32);
        bf16x8 a[4], b[4];
#pragma unroll
        for (int i = 0; i < 4; i++) a[i] = *(const bf16x8*)&lds[cur][0][offA + i * 512];
#pragma unroll
        for (int i = 0; i < 4; i++) b[i] = *(const bf16x8*)&lds[cur][1][offB + i * 512];
#pragma unroll
        for (int i = 0; i < 4; i++)
#pragma unroll
            for (int j = 0; j < 4; j++)
                acc[i][j] = __builtin_amdgcn_mfma_f32_16x16x32_bf16(a[i], b[j], acc[i][j], 0, 0, 0);
        __syncthreads();
        cur ^= 1;
    }
#undef STAGE

    // epilogue: D row = (l>>4)*4 + r (+16*fm), col = l&15 (+16*fn)
    const int row0 = m0 + wm + (l >> 4) * 4;
    const int col0 = n0 + wn + lr;
    float bs[4];
#pragma unroll
    for (int j = 0; j < 4; j++) bs[j] = bias[col0 + j * 16];

    if (MODE == 0) {
        u16* qkv = (u16*)outv;
        const int plane = n0 >> 9;                    // whole block in one plane
        u16* pl = qkv + (size_t)plane * ((size_t)MP * CC);
#pragma unroll
        for (int i = 0; i < 4; i++) {
#pragma unroll
            for (int j = 0; j < 4; j++) {
                int gc = (col0 + j * 16) & 511;
#pragma unroll
                for (int r = 0; r < 4; r++) {
                    int gm = row0 + i * 16 + r;
                    pl[(size_t)gm * CC + gc] = f2bf(acc[i][j][r] + bs[j]);
                }
            }
        }
    } else {
        float* out = (float*)outv;
#pragma unroll
        for (int i = 0; i < 4; i++) {
#pragma unroll
            for (int j = 0; j < 4; j++) {
                int gn = col0 + j * 16;
#pragma unroll
                for (int r = 0; r < 4; r++) {
                    int gm = row0 + i * 16 + r;
                    if (gm < MM) out[(size_t)gm * NSZ + gn] = acc[i][j][r] + bs[j];
                }
            }
        }
    }
}

// ---------------------------------------------------------------------------
// softmax stats over N per (b,c): 8 N-chunks, then merge
// ---------------------------------------------------------------------------
__global__ __launch_bounds__(256) void stats_part_kernel(
    const u16* __restrict__ kbf, float* __restrict__ pmax, float* __restrict__ psum)
{
    int c  = blockIdx.x * 256 + threadIdx.x;
    int b  = blockIdx.y;
    int ch = blockIdx.z;
    int n0 = ch * 128, n1 = (ch == 7) ? NN : n0 + 128;
    const u16* col = kbf + (size_t)(b * NN + n0) * CC + c;
    float m = -1e30f, sum = 0.f;
    for (int n = n0; n < n1; n++, col += CC) {
        float val = bf2f(*col);
        float nm = fmaxf(m, val);
        sum = sum * __expf(m - nm) + __expf(val - nm);
        m = nm;
    }
    pmax[(ch * BB + b) * CC + c] = m;
    psum[(ch * BB + b) * CC + c] = sum;
}

__global__ __launch_bounds__(256) void stats_merge_kernel(
    const float* __restrict__ pmax, const float* __restrict__ psum,
    float* __restrict__ colmax, float* __restrict__ colsum)
{
    int i = blockIdx.x * 256 + threadIdx.x;   // b*CC + c, total 16384
    float m = -1e30f, sum = 0.f;
#pragma unroll
    for (int ch = 0; ch < 8; ch++) {
        float mm = pmax[ch * (BB * CC) + i];
        float ss = psum[ch * (BB * CC) + i];
        float nm = fmaxf(m, mm);
        sum = sum * __expf(m - nm) + ss * __expf(mm - nm);
        m = nm;
    }
    colmax[i] = m;
    colsum[i] = sum;
}

// ---------------------------------------------------------------------------
// ksv[b,h,kk,vv] = sum_n softmax(k)[b,n,h,kk] * v[b,n,h,vv]
// one block per (b,h); 16-row steps, reg->LDS double buffer
// ---------------------------------------------------------------------------
__global__ __launch_bounds__(256) void ksv_kernel(
    const u16* __restrict__ kbf, const u16* __restrict__ vbf,
    const float* __restrict__ colmax, const float* __restrict__ colsum,
    float* __restrict__ ksv)
{
    int bh = blockIdx.x;
    int b = bh >> 3, h = bh & 7;
    __shared__ float ke[2][16][64];
    __shared__ float ve[2][16][64];
    __shared__ float cm[64];

    int t = threadIdx.x;
    int lrow = t >> 4;
    int lcol = (t & 15) * 4;
    int tx = t & 15, ty = t >> 4;
    if (t < 64) cm[t] = colmax[b * CC + h * HD + t];
    __syncthreads();

    u16x4 kreg, vreg;
    {   // prologue load (rows always in-plane thanks to padding)
        size_t off = ((size_t)(b * NN + lrow)) * CC + h * HD + lcol;
        kreg = *(const u16x4*)&kbf[off];
        vreg = *(const u16x4*)&vbf[off];
    }

    float acc[4][4] = {};
    int cur = 0;
    for (int it = 0; it < 65; ++it) {
        int n = it * 16 + lrow;
        bool valid = n < NN;
#pragma unroll
        for (int j = 0; j < 4; j++) {
            ke[cur][lrow][lcol + j] = valid ? __expf(bf2f(kreg[j]) - cm[lcol + j]) : 0.f;
            ve[cur][lrow][lcol + j] = valid ? bf2f(vreg[j]) : 0.f;
        }
        if (it < 64) {
            size_t off = ((size_t)(b * NN + (it + 1) * 16 + lrow)) * CC + h * HD + lcol;
            kreg = *(const u16x4*)&kbf[off];
            vreg = *(const u16x4*)&vbf[off];
        }
        __syncthreads();
#pragma unroll 4
        for (int d = 0; d < 16; d++) {
            f32x4 ka = *(const f32x4*)&ke[cur][d][ty * 4];
            f32x4 vb = *(const f32x4*)&ve[cur][d][tx * 4];
#pragma unroll
            for (int i = 0; i < 4; i++)
#pragma unroll
                for (int j = 0; j < 4; j++)
                    acc[i][j] = fmaf(ka[i], vb[j], acc[i][j]);
        }
        cur ^= 1;
    }

#pragma unroll
    for (int i = 0; i < 4; i++) {
        float inv = 1.f / colsum[b * CC + h * HD + ty * 4 + i];
#pragma unroll
        for (int j = 0; j < 4; j++)
            ksv[(size_t)bh * 4096 + (ty * 4 + i) * 64 + tx * 4 + j] = acc[i][j] * inv;
    }
}

// ---------------------------------------------------------------------------
// attbf[b,n,h,:] = bf16(SCALE * q[b,n,h,:] @ ksv[b,h,:,:])
// ---------------------------------------------------------------------------
__global__ __launch_bounds__(256) void factor_att_kernel(
    const u16* __restrict__ qbf, const float* __restrict__ ksv, u16* __restrict__ attbf)
{
    int bh = blockIdx.y;
    int b = bh >> 3, h = bh & 7;
    int n0 = blockIdx.x * 64;
    __shared__ float qs[64][68];   // [kk][row]
    __shared__ float ks[64][68];   // [kk][vv]

    int t = threadIdx.x;
    int tx = t & 15, ty = t >> 4;

    const float* kbase = ksv + (size_t)bh * 4096;
#pragma unroll
    for (int i = 0; i < 4; i++) {
        int fidx = t + i * 256;                 // float4 index
        int kk = fidx >> 4, vv = (fidx & 15) * 4;
        *(f32x4*)&ks[kk][vv] = *(const f32x4*)&kbase[(size_t)fidx * 4];
    }
#pragma unroll
    for (int i = 0; i < 4; i++) {
        int e = t + i * 256;                    // u16x4 index
        int row = e >> 4, cc0 = (e & 15) * 4;
        // rows may exceed NN but stay inside padded planes -> safe unguarded
        u16x4 qv = *(const u16x4*)&qbf[((size_t)(b * NN + n0 + row)) * CC + h * HD + cc0];
#pragma unroll
        for (int j = 0; j < 4; j++) qs[cc0 + j][row] = bf2f(qv[j]);
    }
    __syncthreads();

    float acc[4][4] = {};
#pragma unroll 8
    for (int kk = 0; kk < 64; kk++) {
        f32x4 a4 = *(const f32x4*)&qs[kk][ty * 4];
        f32x4 b4 = *(const f32x4*)&ks[kk][tx * 4];
#pragma unroll
        for (int i = 0; i < 4; i++)
#pragma unroll
            for (int j = 0; j < 4; j++)
                acc[i][j] = fmaf(a4[i], b4[j], acc[i][j]);
    }

#pragma unroll
    for (int i = 0; i < 4; i++) {
        int n = n0 + ty * 4 + i;
        if (n >= NN) continue;
        u16x4 o;
#pragma unroll
        for (int j = 0; j < 4; j++) o[j] = f2bf(SCALE * acc[i][j]);
        *(u16x4*)&attbf[((size_t)(b * NN + n)) * CC + h * HD + tx * 4] = o;
    }
}

// ---------------------------------------------------------------------------
// CRPE: attbf[b,1+pix,c..c+8] += q * (dwconv(v)+cb); 8 channels per thread
// ---------------------------------------------------------------------------
__global__ __launch_bounds__(256) void conv_ev_kernel(
    const u16* __restrict__ vbf, const u16* __restrict__ qbf,
    const float* __restrict__ ck3, const float* __restrict__ cb3,
    const float* __restrict__ ck5, const float* __restrict__ cb5,
    const float* __restrict__ ck7, const float* __restrict__ cb7,
    u16* __restrict__ attbf)
{
    int t = blockIdx.x * 256 + threadIdx.x;   // 32*1024*64
    int cg  = t & 63;
    int pix = (t >> 6) & 1023;
    int b   = t >> 16;
    int c   = cg * 8;
    int y = pix >> 5, x = pix & 31;

    const float* w; const float* cb; int ksz, nch, cl;
    if (c < 128)      { ksz = 3; nch = 128; cl = c;       w = ck3; cb = cb3; }
    else if (c < 320) { ksz = 5; nch = 192; cl = c - 128; w = ck5; cb = cb5; }
    else              { ksz = 7; nch = 192; cl = c - 320; w = ck7; cb = cb7; }
    int pad = ksz >> 1;

    float sum[8];
    {
        f32x4 b0 = *(const f32x4*)&cb[cl];
        f32x4 b1 = *(const f32x4*)&cb[cl + 4];
#pragma unroll
        for (int j = 0; j < 4; j++) { sum[j] = b0[j]; sum[j + 4] = b1[j]; }
    }

    for (int dy = -pad; dy <= pad; dy++) {
        int yy = y + dy;
        if (yy < 0 || yy >= 32) continue;
        for (int dx = -pad; dx <= pad; dx++) {
            int xx = x + dx;
            if (xx < 0 || xx >= 32) continue;
            int tap = (dy + pad) * ksz + (dx + pad);
            u16x8 vv = *(const u16x8*)&vbf[((size_t)(b * NN) + 1 + yy * 32 + xx) * CC + c];
            f32x4 w0 = *(const f32x4*)&w[(size_t)tap * nch + cl];
            f32x4 w1 = *(const f32x4*)&w[(size_t)tap * nch + cl + 4];
#pragma unroll
            for (int j = 0; j < 4; j++) {
                sum[j]     = fmaf(bf2f(vv[j]),     w0[j], sum[j]);
                sum[j + 4] = fmaf(bf2f(vv[j + 4]), w1[j], sum[j + 4]);
            }
        }
    }

    size_t o = ((size_t)(b * NN) + 1 + pix) * CC + c;
    u16x8 qv = *(const u16x8*)&qbf[o];
    u16x8 av = *(const u16x8*)&attbf[o];
    u16x8 ov;
#pragma unroll
    for (int j = 0; j < 8; j++)
        ov[j] = f2bf(bf2f(av[j]) + bf2f(qv[j]) * sum[j]);
    *(u16x8*)&attbf[o] = ov;
}

// ---------------------------------------------------------------------------
extern "C" void kernel_launch(void* const* d_in, const int* in_sizes, int n_in,
                              void* d_out, int out_size, void* d_ws, size_t ws_size,
                              hipStream_t stream)
{
    const float* x     = (const float*)d_in[0];
    const float* Wqkv  = (const float*)d_in[1];
    const float* bqkv  = (const float*)d_in[2];
    const float* Wproj = (const float*)d_in[3];
    const float* bproj = (const float*)d_in[4];
    const float* ck3   = (const float*)d_in[5];
    const float* cb3   = (const float*)d_in[6];
    const float* ck5   = (const float*)d_in[7];
    const float* cb5   = (const float*)d_in[8];
    const float* ck7   = (const float*)d_in[9];
    const float* cb7   = (const float*)d_in[10];
    float* out = (float*)d_out;

    const size_t PLANE = (size_t)MP * CC;    // 16,842,752 elems

    u16* xbf  = (u16*)d_ws;                  // PLANE         (reused as attbf)
    u16* qbf  = xbf + PLANE;                 // q plane
    u16* kbf  = qbf + PLANE;
    u16* vbf  = kbf + PLANE;
    u16* wqT  = vbf + PLANE;                 // 1536*512
    u16* wpT  = wqT + (size_t)1536 * 512;    // 512*512
    float* pmax   = (float*)(wpT + (size_t)512 * 512);
    float* psum   = pmax + 8 * BB * CC;
    float* colmax = psum + 8 * BB * CC;
    float* colsum = colmax + BB * CC;
    float* ksv    = colsum + BB * CC;        // 256*4096 floats
    u16* attbf = xbf;                        // alias (x dead after qkv GEMM)

    // 1) converts
    convert_x_kernel<<<(MP * CC / 8 + 255) / 256, 256, 0, stream>>>(x, xbf);
    convert_wt_kernel<<<1536 * 64 / 256, 256, 0, stream>>>(Wqkv, wqT, 1536);
    convert_wt_kernel<<<512 * 64 / 256, 256, 0, stream>>>(Wproj, wpT, 512);

    // 2) qkv GEMM -> bf16 q/k/v planes
    {
        dim3 grid(1536 / 128, MP / 128);
        gemm_bf16_kernel<0, 1536><<<grid, 256, 0, stream>>>(xbf, wqT, bqkv, qbf);
    }
    // 3) softmax stats
    {
        dim3 grid(CC / 256, BB, 8);
        stats_part_kernel<<<grid, 256, 0, stream>>>(kbf, pmax, psum);
        stats_merge_kernel<<<BB * CC / 256, 256, 0, stream>>>(pmax, psum, colmax, colsum);
    }
    // 4) ksv
    ksv_kernel<<<BB * HH, 256, 0, stream>>>(kbf, vbf, colmax, colsum, ksv);
    // 5) factor att -> attbf (overlays xbf)
    {
        dim3 grid((NN + 63) / 64, BB * HH);
        factor_att_kernel<<<grid, 256, 0, stream>>>(qbf, ksv, attbf);
    }
    // 6) CRPE
    conv_ev_kernel<<<BB * 1024 * 64 / 256, 256, 0, stream>>>(
        vbf, qbf, ck3, cb3, ck5, cb5, ck7, cb7, attbf);
    // 7) proj GEMM -> out
    {
        dim3 grid(512 / 128, MP / 128);
        gemm_bf16_kernel<1, 512><<<grid, 256, 0, stream>>>(attbf, wpT, bproj, out);
    }
}

// Round 3
// 360.998 us; speedup vs baseline: 4.7713x; 1.1524x over previous
//
#include <hip/hip_runtime.h>
#include <hip/hip_bf16.h>

#define BB 32
#define NN 1025
#define CC 512
#define HH 8
#define HD 64
#define MM (BB * NN)        // 32800
#define MP 32896            // 257 * 128 (padded M)
#define KK 512
#define SCALE 0.125f

typedef unsigned short u16;
typedef __attribute__((ext_vector_type(4))) unsigned short u16x4;
typedef __attribute__((ext_vector_type(8))) unsigned short u16x8;
typedef __attribute__((ext_vector_type(4))) float f32x4;
typedef __attribute__((ext_vector_type(8))) __bf16 bf16x8;

__device__ __forceinline__ u16 f2bf(float f) {
    unsigned u = __float_as_uint(f);
    unsigned r = (u + 0x7FFFu + ((u >> 16) & 1u)) >> 16;
    return (u16)r;
}
__device__ __forceinline__ float bf2f(u16 h) {
    return __uint_as_float((unsigned)h << 16);
}

__device__ __forceinline__ void gload16(const u16* g, u16* l) {
    __builtin_amdgcn_global_load_lds(
        (const __attribute__((address_space(1))) unsigned int*)g,
        (__attribute__((address_space(3))) unsigned int*)l, 16, 0, 0);
}

// ---------------------------------------------------------------------------
// convert x (fp32 [MM][512]) -> xbf (bf16 [MP][512]), zero pad rows
// ---------------------------------------------------------------------------
__global__ __launch_bounds__(256) void convert_x_kernel(
    const float* __restrict__ x, u16* __restrict__ xbf)
{
    size_t t = (size_t)blockIdx.x * 256 + threadIdx.x;
    size_t base = t * 8;
    u16x8 o;
    if (base < (size_t)MM * CC) {
        f32x4 a = *(const f32x4*)&x[base];
        f32x4 b = *(const f32x4*)&x[base + 4];
#pragma unroll
        for (int j = 0; j < 4; j++) { o[j] = f2bf(a[j]); o[j + 4] = f2bf(b[j]); }
    } else {
#pragma unroll
        for (int j = 0; j < 8; j++) o[j] = 0;
    }
    *(u16x8*)&xbf[base] = o;
}

// ---------------------------------------------------------------------------
// transpose+convert weights: Wt[n][k] = bf16(W[k][n]);  K = 512
// ---------------------------------------------------------------------------
__global__ __launch_bounds__(256) void convert_wt_kernel(
    const float* __restrict__ W, u16* __restrict__ Wt, int N)
{
    int t = blockIdx.x * 256 + threadIdx.x;
    int n = t >> 6;
    int k0 = (t & 63) * 8;
    u16x8 o;
#pragma unroll
    for (int j = 0; j < 8; j++) o[j] = f2bf(W[(size_t)(k0 + j) * N + n]);
    *(u16x8*)&Wt[(size_t)n * KK + k0] = o;
}

// ---------------------------------------------------------------------------
// expand conv weights into dense [7][7][512] table (+ merged bias [512])
// ---------------------------------------------------------------------------
__global__ __launch_bounds__(256) void prep_w7_kernel(
    const float* __restrict__ ck3, const float* __restrict__ cb3,
    const float* __restrict__ ck5, const float* __restrict__ cb5,
    const float* __restrict__ ck7, const float* __restrict__ cb7,
    float* __restrict__ w7, float* __restrict__ cbx)
{
    int t = blockIdx.x * 256 + threadIdx.x;   // 49*512 = 25088
    if (t >= 49 * 512) return;
    int c = t & 511;
    int tap = t >> 9;
    int dy = tap / 7, dx = tap % 7;
    float w = 0.f;
    if (c < 128) {
        int ry = dy - 2, rx = dx - 2;
        if (ry >= 0 && ry < 3 && rx >= 0 && rx < 3) w = ck3[(ry * 3 + rx) * 128 + c];
    } else if (c < 320) {
        int ry = dy - 1, rx = dx - 1;
        if (ry >= 0 && ry < 5 && rx >= 0 && rx < 5) w = ck5[(ry * 5 + rx) * 192 + (c - 128)];
    } else {
        w = ck7[(dy * 7 + dx) * 192 + (c - 320)];
    }
    w7[tap * 512 + c] = w;
    if (t < 512)
        cbx[t] = (t < 128) ? cb3[t] : (t < 320) ? cb5[t - 128] : cb7[t - 320];
}

// ---------------------------------------------------------------------------
// bf16 MFMA GEMM: out = A[MP][512] @ Bt[N][512]^T + bias
// ---------------------------------------------------------------------------
template <int MODE, int NSZ>
__global__ __launch_bounds__(256) void gemm_bf16_kernel(
    const u16* __restrict__ A, const u16* __restrict__ Bt,
    const float* __restrict__ bias, void* __restrict__ outv)
{
    __shared__ __align__(16) u16 lds[2][2][4096];

    const int t  = threadIdx.x;
    const int m0 = blockIdx.y * 128;
    const int n0 = blockIdx.x * 128;

    const int srow = t >> 2;
    const int ps   = t & 3;
    const int ls   = ps ^ ((srow >> 1) & 3);
    const u16* gA = A  + (size_t)(m0 + srow) * KK + ls * 8;
    const u16* gB = Bt + (size_t)(n0 + srow) * KK + ls * 8;

    const int l  = t & 63;
    const int w  = t >> 6;
    const int wm = (w >> 1) * 64;
    const int wn = (w & 1) * 64;
    const int lr = l & 15;
    const int s  = l >> 4;
    const int ra = wm + lr;
    const int rb = wn + lr;
    const int offA = ra * 32 + (s ^ ((ra >> 1) & 3)) * 8;
    const int offB = rb * 32 + (s ^ ((rb >> 1) & 3)) * 8;

    f32x4 acc[4][4] = {};

#define STAGE(buf, kk_) do {                                        \
        gload16(gA + (kk_),           &lds[buf][0][t * 8]);         \
        gload16(gA + 64 * KK + (kk_), &lds[buf][0][2048 + t * 8]);  \
        gload16(gB + (kk_),           &lds[buf][1][t * 8]);         \
        gload16(gB + 64 * KK + (kk_), &lds[buf][1][2048 + t * 8]);  \
    } while (0)

    STAGE(0, 0);
    __syncthreads();

    int cur = 0;
    for (int step = 0; step < 16; ++step) {
        if (step < 15) STAGE(cur ^ 1, (step + 1) * 32);
        bf16x8 a[4], b[4];
#pragma unroll
        for (int i = 0; i < 4; i++) a[i] = *(const bf16x8*)&lds[cur][0][offA + i * 512];
#pragma unroll
        for (int i = 0; i < 4; i++) b[i] = *(const bf16x8*)&lds[cur][1][offB + i * 512];
#pragma unroll
        for (int i = 0; i < 4; i++)
#pragma unroll
            for (int j = 0; j < 4; j++)
                acc[i][j] = __builtin_amdgcn_mfma_f32_16x16x32_bf16(a[i], b[j], acc[i][j], 0, 0, 0);
        __syncthreads();
        cur ^= 1;
    }
#undef STAGE

    const int row0 = m0 + wm + (l >> 4) * 4;
    const int col0 = n0 + wn + lr;
    float bs[4];
#pragma unroll
    for (int j = 0; j < 4; j++) bs[j] = bias[col0 + j * 16];

    if (MODE == 0) {
        u16* qkv = (u16*)outv;
        const int plane = n0 >> 9;
        u16* pl = qkv + (size_t)plane * ((size_t)MP * CC);
#pragma unroll
        for (int i = 0; i < 4; i++) {
#pragma unroll
            for (int j = 0; j < 4; j++) {
                int gc = (col0 + j * 16) & 511;
#pragma unroll
                for (int r = 0; r < 4; r++) {
                    int gm = row0 + i * 16 + r;
                    pl[(size_t)gm * CC + gc] = f2bf(acc[i][j][r] + bs[j]);
                }
            }
        }
    } else {
        float* out = (float*)outv;
#pragma unroll
        for (int i = 0; i < 4; i++) {
#pragma unroll
            for (int j = 0; j < 4; j++) {
                int gn = col0 + j * 16;
#pragma unroll
                for (int r = 0; r < 4; r++) {
                    int gm = row0 + i * 16 + r;
                    if (gm < MM) out[(size_t)gm * NSZ + gn] = acc[i][j][r] + bs[j];
                }
            }
        }
    }
}

// ---------------------------------------------------------------------------
// softmax stats over N per (b,c): 8 N-chunks, then merge
// ---------------------------------------------------------------------------
__global__ __launch_bounds__(256) void stats_part_kernel(
    const u16* __restrict__ kbf, float* __restrict__ pmax, float* __restrict__ psum)
{
    int c  = blockIdx.x * 256 + threadIdx.x;
    int b  = blockIdx.y;
    int ch = blockIdx.z;
    int n0 = ch * 128, n1 = (ch == 7) ? NN : n0 + 128;
    const u16* col = kbf + (size_t)(b * NN + n0) * CC + c;
    float m = -1e30f, sum = 0.f;
    for (int n = n0; n < n1; n++, col += CC) {
        float val = bf2f(*col);
        float nm = fmaxf(m, val);
        sum = sum * __expf(m - nm) + __expf(val - nm);
        m = nm;
    }
    pmax[(ch * BB + b) * CC + c] = m;
    psum[(ch * BB + b) * CC + c] = sum;
}

__global__ __launch_bounds__(256) void stats_merge_kernel(
    const float* __restrict__ pmax, const float* __restrict__ psum,
    float* __restrict__ colmax, float* __restrict__ colsum)
{
    int i = blockIdx.x * 256 + threadIdx.x;
    float m = -1e30f, sum = 0.f;
#pragma unroll
    for (int ch = 0; ch < 8; ch++) {
        float mm = pmax[ch * (BB * CC) + i];
        float ss = psum[ch * (BB * CC) + i];
        float nm = fmaxf(m, mm);
        sum = sum * __expf(m - nm) + ss * __expf(mm - nm);
        m = nm;
    }
    colmax[i] = m;
    colsum[i] = sum;
}

// ---------------------------------------------------------------------------
// ksv[b,h,kk,vv] = sum_n softmax(k)[b,n,h,kk] * v[b,n,h,vv]
// ---------------------------------------------------------------------------
__global__ __launch_bounds__(256) void ksv_kernel(
    const u16* __restrict__ kbf, const u16* __restrict__ vbf,
    const float* __restrict__ colmax, const float* __restrict__ colsum,
    float* __restrict__ ksv)
{
    int bh = blockIdx.x;
    int b = bh >> 3, h = bh & 7;
    __shared__ float ke[2][16][64];
    __shared__ float ve[2][16][64];
    __shared__ float cm[64];

    int t = threadIdx.x;
    int lrow = t >> 4;
    int lcol = (t & 15) * 4;
    int tx = t & 15, ty = t >> 4;
    if (t < 64) cm[t] = colmax[b * CC + h * HD + t];
    __syncthreads();

    u16x4 kreg, vreg;
    {
        size_t off = ((size_t)(b * NN + lrow)) * CC + h * HD + lcol;
        kreg = *(const u16x4*)&kbf[off];
        vreg = *(const u16x4*)&vbf[off];
    }

    float acc[4][4] = {};
    int cur = 0;
    for (int it = 0; it < 65; ++it) {
        int n = it * 16 + lrow;
        bool valid = n < NN;
#pragma unroll
        for (int j = 0; j < 4; j++) {
            ke[cur][lrow][lcol + j] = valid ? __expf(bf2f(kreg[j]) - cm[lcol + j]) : 0.f;
            ve[cur][lrow][lcol + j] = valid ? bf2f(vreg[j]) : 0.f;
        }
        if (it < 64) {
            size_t off = ((size_t)(b * NN + (it + 1) * 16 + lrow)) * CC + h * HD + lcol;
            kreg = *(const u16x4*)&kbf[off];
            vreg = *(const u16x4*)&vbf[off];
        }
        __syncthreads();
#pragma unroll 4
        for (int d = 0; d < 16; d++) {
            f32x4 ka = *(const f32x4*)&ke[cur][d][ty * 4];
            f32x4 vb = *(const f32x4*)&ve[cur][d][tx * 4];
#pragma unroll
            for (int i = 0; i < 4; i++)
#pragma unroll
                for (int j = 0; j < 4; j++)
                    acc[i][j] = fmaf(ka[i], vb[j], acc[i][j]);
        }
        cur ^= 1;
    }

#pragma unroll
    for (int i = 0; i < 4; i++) {
        float inv = 1.f / colsum[b * CC + h * HD + ty * 4 + i];
#pragma unroll
        for (int j = 0; j < 4; j++)
            ksv[(size_t)bh * 4096 + (ty * 4 + i) * 64 + tx * 4 + j] = acc[i][j] * inv;
    }
}

// ---------------------------------------------------------------------------
// attbf[b,n,h,:] = bf16(SCALE * q[b,n,h,:] @ ksv[b,h,:,:])
// ---------------------------------------------------------------------------
__global__ __launch_bounds__(256) void factor_att_kernel(
    const u16* __restrict__ qbf, const float* __restrict__ ksv, u16* __restrict__ attbf)
{
    int bh = blockIdx.y;
    int b = bh >> 3, h = bh & 7;
    int n0 = blockIdx.x * 64;
    __shared__ float qs[64][68];
    __shared__ float ks[64][68];

    int t = threadIdx.x;
    int tx = t & 15, ty = t >> 4;

    const float* kbase = ksv + (size_t)bh * 4096;
#pragma unroll
    for (int i = 0; i < 4; i++) {
        int fidx = t + i * 256;
        int kk = fidx >> 4, vv = (fidx & 15) * 4;
        *(f32x4*)&ks[kk][vv] = *(const f32x4*)&kbase[(size_t)fidx * 4];
    }
#pragma unroll
    for (int i = 0; i < 4; i++) {
        int e = t + i * 256;
        int row = e >> 4, cc0 = (e & 15) * 4;
        u16x4 qv = *(const u16x4*)&qbf[((size_t)(b * NN + n0 + row)) * CC + h * HD + cc0];
#pragma unroll
        for (int j = 0; j < 4; j++) qs[cc0 + j][row] = bf2f(qv[j]);
    }
    __syncthreads();

    float acc[4][4] = {};
#pragma unroll 8
    for (int kk = 0; kk < 64; kk++) {
        f32x4 a4 = *(const f32x4*)&qs[kk][ty * 4];
        f32x4 b4 = *(const f32x4*)&ks[kk][tx * 4];
#pragma unroll
        for (int i = 0; i < 4; i++)
#pragma unroll
            for (int j = 0; j < 4; j++)
                acc[i][j] = fmaf(a4[i], b4[j], acc[i][j]);
    }

#pragma unroll
    for (int i = 0; i < 4; i++) {
        int n = n0 + ty * 4 + i;
        if (n >= NN) continue;
        u16x4 o;
#pragma unroll
        for (int j = 0; j < 4; j++) o[j] = f2bf(SCALE * acc[i][j]);
        *(u16x4*)&attbf[((size_t)(b * NN + n)) * CC + h * HD + tx * 4] = o;
    }
}

// ---------------------------------------------------------------------------
// CRPE v2: uniform 49-tap conv with expanded weights, 8x8 register blocking.
// Block = (b, y): 256 threads = 4 x-octets (one per wave) x 64 channel-groups.
// attbf[b,1+y*32+x, c8] += q * (conv + bias)
// ---------------------------------------------------------------------------
__global__ __launch_bounds__(256) void conv_ev2_kernel(
    const u16* __restrict__ vbf, const u16* __restrict__ qbf,
    const float* __restrict__ w7, const float* __restrict__ cbx,
    u16* __restrict__ attbf)
{
    int by = blockIdx.x;            // b*32 + y
    int b = by >> 5, y = by & 31;
    int t = threadIdx.x;
    int xo = t >> 6;                // wave-uniform x-octet
    int cg = t & 63;
    int c = cg * 8;
    const int x0 = xo * 8;

    float acc[8][8];
    {
        f32x4 b0 = *(const f32x4*)&cbx[c];
        f32x4 b1 = *(const f32x4*)&cbx[c + 4];
#pragma unroll
        for (int xi = 0; xi < 8; xi++)
#pragma unroll
            for (int j = 0; j < 4; j++) { acc[xi][j] = b0[j]; acc[xi][j + 4] = b1[j]; }
    }

    for (int dy = 0; dy < 7; dy++) {
        int yy = y + dy - 3;
        if (yy < 0 || yy >= 32) continue;            // block-uniform
        float wr[7][8];
#pragma unroll
        for (int dx = 0; dx < 7; dx++) {
            *(f32x4*)&wr[dx][0] = *(const f32x4*)&w7[(dy * 7 + dx) * 512 + c];
            *(f32x4*)&wr[dx][4] = *(const f32x4*)&w7[(dy * 7 + dx) * 512 + c + 4];
        }
        const u16* vrow = vbf + ((size_t)(b * NN) + 1 + (size_t)yy * 32) * CC + c;
#pragma unroll
        for (int sxi = 0; sxi < 14; sxi++) {
            int sx = x0 - 3 + sxi;
            if (sx < 0 || sx >= 32) continue;        // wave-uniform
            u16x8 vv = *(const u16x8*)&vrow[(size_t)sx * CC];
            float vf[8];
#pragma unroll
            for (int j = 0; j < 8; j++) vf[j] = bf2f(vv[j]);
            int lo = sxi - 6 > 0 ? sxi - 6 : 0;
            int hi = sxi < 7 ? sxi : 7;
#pragma unroll
            for (int xi = 0; xi < 8; xi++) {
                if (xi < lo || xi > hi) continue;    // compile-time after unroll
                int dx = sxi - xi;
#pragma unroll
                for (int j = 0; j < 8; j++)
                    acc[xi][j] = fmaf(vf[j], wr[dx][j], acc[xi][j]);
            }
        }
    }

#pragma unroll
    for (int xi = 0; xi < 8; xi++) {
        size_t o = ((size_t)(b * NN) + 1 + (size_t)y * 32 + x0 + xi) * CC + c;
        u16x8 qv = *(const u16x8*)&qbf[o];
        u16x8 av = *(const u16x8*)&attbf[o];
        u16x8 ov;
#pragma unroll
        for (int j = 0; j < 8; j++)
            ov[j] = f2bf(bf2f(av[j]) + bf2f(qv[j]) * acc[xi][j]);
        *(u16x8*)&attbf[o] = ov;
    }
}

// ---------------------------------------------------------------------------
extern "C" void kernel_launch(void* const* d_in, const int* in_sizes, int n_in,
                              void* d_out, int out_size, void* d_ws, size_t ws_size,
                              hipStream_t stream)
{
    const float* x     = (const float*)d_in[0];
    const float* Wqkv  = (const float*)d_in[1];
    const float* bqkv  = (const float*)d_in[2];
    const float* Wproj = (const float*)d_in[3];
    const float* bproj = (const float*)d_in[4];
    const float* ck3   = (const float*)d_in[5];
    const float* cb3   = (const float*)d_in[6];
    const float* ck5   = (const float*)d_in[7];
    const float* cb5   = (const float*)d_in[8];
    const float* ck7   = (const float*)d_in[9];
    const float* cb7   = (const float*)d_in[10];
    float* out = (float*)d_out;

    const size_t PLANE = (size_t)MP * CC;

    u16* xbf  = (u16*)d_ws;
    u16* qbf  = xbf + PLANE;
    u16* kbf  = qbf + PLANE;
    u16* vbf  = kbf + PLANE;
    u16* wqT  = vbf + PLANE;
    u16* wpT  = wqT + (size_t)1536 * 512;
    float* pmax   = (float*)(wpT + (size_t)512 * 512);
    float* psum   = pmax + 8 * BB * CC;
    float* colmax = psum + 8 * BB * CC;
    float* colsum = colmax + BB * CC;
    float* ksv    = colsum + BB * CC;          // 256*4096 floats
    float* w7     = ksv + (size_t)256 * 4096;  // 49*512
    float* cbx    = w7 + 49 * 512;             // 512
    u16* attbf = xbf;

    // 1) converts + conv-weight expansion
    convert_x_kernel<<<(MP * CC / 8 + 255) / 256, 256, 0, stream>>>(x, xbf);
    convert_wt_kernel<<<1536 * 64 / 256, 256, 0, stream>>>(Wqkv, wqT, 1536);
    convert_wt_kernel<<<512 * 64 / 256, 256, 0, stream>>>(Wproj, wpT, 512);
    prep_w7_kernel<<<98, 256, 0, stream>>>(ck3, cb3, ck5, cb5, ck7, cb7, w7, cbx);

    // 2) qkv GEMM -> bf16 q/k/v planes
    {
        dim3 grid(1536 / 128, MP / 128);
        gemm_bf16_kernel<0, 1536><<<grid, 256, 0, stream>>>(xbf, wqT, bqkv, qbf);
    }
    // 3) softmax stats
    {
        dim3 grid(CC / 256, BB, 8);
        stats_part_kernel<<<grid, 256, 0, stream>>>(kbf, pmax, psum);
        stats_merge_kernel<<<BB * CC / 256, 256, 0, stream>>>(pmax, psum, colmax, colsum);
    }
    // 4) ksv
    ksv_kernel<<<BB * HH, 256, 0, stream>>>(kbf, vbf, colmax, colsum, ksv);
    // 5) factor att -> attbf (overlays xbf)
    {
        dim3 grid((NN + 63) / 64, BB * HH);
        factor_att_kernel<<<grid, 256, 0, stream>>>(qbf, ksv, attbf);
    }
    // 6) CRPE v2
    conv_ev2_kernel<<<BB * 32, 256, 0, stream>>>(vbf, qbf, w7, cbx, attbf);
    // 7) proj GEMM -> out
    {
        dim3 grid(512 / 128, MP / 128);
        gemm_bf16_kernel<1, 512><<<grid, 256, 0, stream>>>(attbf, wpT, bproj, out);
    }
}